// Round 2
// baseline (73.132 us; speedup 1.0000x reference)
//
#include <hip/hip_runtime.h>
#include <math.h>

#define BB 4
#define HH 256
#define WW 256
#define NN (BB*HH*WW)          // 262144
typedef unsigned long long u64;
typedef unsigned int u32;

#define SENT 100000            // no-zero-in-column sentinel (g^2 ~1e10 >> 130050 max real)

// Module-global ticket counter for last-block detection.
// Each iteration adds exactly 256, so (old & 255) == 255 identifies the last
// arriving block of THIS iteration regardless of how many graph replays ran.
// (2^32 is a multiple of 256, so wraparound preserves the invariant.)
__device__ unsigned g_ticket = 0u;

// ws layout: float partial[block][8], blocks 0..255, only [0..5] used.
// Cacheline-padded plain stores by one thread per block + threadfence + ticket.

// ---------------------------------------------------------------------------
// Single fused kernel. grid = 256 blocks (b, 4-row band) x 512 threads.
//   phase 1: thread (img, w, c4) loads 64 float4 (rows 64w..64w+63,
//            cols 4c4..4c4+3) -> builds 4 column mask words -> LDS MSK
//            (padded 9 u32/column: gcd(9,32)=1, conflict-free reads).
//   phase 2: thread (img, c) bit-scans its column's 4 words -> G (vertical g^2)
//   phase 3: thread (img, j) outward min-plus scan (img-uniform waves ->
//            coherent __all early exit) -> D = sqrt(d2)
//   phase 4: 512 threads x 2 pixels (float2, hoisted loads) loss terms,
//            block reduce, tid==0 stores 6 partials + threadfence + ticket.
//   phase 5: last-arriving block reduces 256x6 partials (coherent atomic
//            reads) and writes the scalar loss.
// ---------------------------------------------------------------------------
__global__ __launch_bounds__(512)
void fused_all(const float* __restrict__ pred,
               const float* __restrict__ targ,
               float* __restrict__ partial,
               float* __restrict__ out) {
    __shared__ u32   MSK[2][WW][9];   // [img][col][word*2+half], pad to 9
    __shared__ float G[2][4][WW];     // vertical g^2  [img][band row][col]
    __shared__ float D[2][4][WW];     // sqrt(d2)      [img][band row][col]
    __shared__ float red[8][6];
    __shared__ int   amLast;

    int blk  = blockIdx.x;          // 0..255
    int b    = blk >> 6;
    int band = blk & 63;
    int i0   = band << 2;           // first row of band
    int wq   = i0 >> 6;             // 64-row word containing the band
    int o0   = i0 & 63;             // bit offset (<=60, so o0+3 <= 63)

    int tid  = threadIdx.x;
    int img  = tid >> 8;            // waves 0-3: pred, waves 4-7: targ

    // ---- hoisted phase-4 input loads (consumed after phase 3; L2 latency
    //      hides under phases 1-3)
    int k4   = tid >> 7;            // band row 0..3 of this thread's 2 pixels
    int j4   = (tid << 1) & 255;    // first col of the float2
    int idx4 = (b * HH + (i0 + k4)) * WW + j4;
    float2 xv = *(const float2*)(pred + idx4);
    float2 tv = *(const float2*)(targ + idx4);

    // ---- phase 1: build column zero-masks with float4 loads, stage in LDS
    {
        int r8 = tid & 255;
        int w  = r8 >> 6;           // word index 0..3 (rows 64w..64w+63)
        int c4 = r8 & 63;           // column group (cols 4c4..4c4+3)
        const float* s = (img ? targ : pred) + b * (HH * WW)
                       + (w * 64) * WW + (c4 * 4);
        u64 m0 = 0, m1 = 0, m2 = 0, m3 = 0;
        #pragma unroll
        for (int rr = 0; rr < 64; ++rr) {
            float4 v = *(const float4*)(s + rr * WW);
            m0 |= ((u64)(v.x <= 0.5f)) << rr;
            m1 |= ((u64)(v.y <= 0.5f)) << rr;
            m2 |= ((u64)(v.z <= 0.5f)) << rr;
            m3 |= ((u64)(v.w <= 0.5f)) << rr;
        }
        u64 mm[4] = { m0, m1, m2, m3 };
        #pragma unroll
        for (int k = 0; k < 4; ++k) {
            MSK[img][c4 * 4 + k][2 * w]     = (u32)mm[k];
            MSK[img][c4 * 4 + k][2 * w + 1] = (u32)(mm[k] >> 32);
        }
    }
    __syncthreads();

    // ---- phase 2: vertical distances for the band's 4 rows (verified bit logic)
    int c = tid & 255;              // this thread's column
    {
        const u32* mp = MSK[img][c];
        u64 M0 = (u64)mp[0] | ((u64)mp[1] << 32);
        u64 M1 = (u64)mp[2] | ((u64)mp[3] << 32);
        u64 M2 = (u64)mp[4] | ((u64)mp[5] << 32);
        u64 M3 = (u64)mp[6] | ((u64)mp[7] << 32);

        // per-word first (lowest) set-bit global index, sentinel SENT
        int t1 = __ffsll(M1), t2 = __ffsll(M2), t3 = __ffsll(M3);
        int f1 = t1 ? 64 + t1 - 1  : SENT;
        int f2 = t2 ? 128 + t2 - 1 : SENT;
        int f3 = t3 ? 192 + t3 - 1 : SENT;
        // per-word last (highest) set-bit global index, sentinel -SENT
        int r0 = __ffsll(__brevll(M0));
        int r1 = __ffsll(__brevll(M1));
        int r2 = __ffsll(__brevll(M2));
        int l0 = r0 ? 64 - r0  : -SENT;
        int l1 = r1 ? 128 - r1 : -SENT;
        int l2 = r2 ? 192 - r2 : -SENT;

        int s3 = f3;
        int s2 = min(f2, s3);
        int s1 = min(f1, s2);
        int NF = (wq == 0) ? s1 : (wq == 1) ? s2 : (wq == 2) ? s3 : SENT;
        int q0 = l0;
        int q1 = max(q0, l1);
        int q2 = max(q1, l2);
        int PB = (wq == 0) ? -SENT : (wq == 1) ? q0 : (wq == 2) ? q1 : q2;
        u64 Mq = (wq == 0) ? M0 : (wq == 1) ? M1 : (wq == 2) ? M2 : M3;

        #pragma unroll
        for (int kk = 0; kk < 4; ++kk) {
            int i = i0 + kk, o = o0 + kk;            // o <= 63
            u64 sh  = Mq >> o;                       // bits at/above i within word
            int tn  = __ffsll(sh);
            int n   = tn ? i + tn - 1 : NF;          // nearest zero row >= i
            u64 shl = Mq << (63 - o);                // bits at/below i within word
            int tp  = __ffsll(__brevll(shl));
            int p   = tp ? i - (tp - 1) : PB;        // nearest zero row <= i
            int g   = min(n - i, i - p);
            G[img][kk][c] = (float)g * (float)g;
        }
    }
    __syncthreads();

    // ---- phase 3: horizontal min-plus, outward scan, one image per thread
    {
        int j = c;
        float d2[4];
        #pragma unroll
        for (int k = 0; k < 4; ++k)
            d2[k] = G[img][k][j];                    // r = 0 candidate
        for (int r = 1; r < WW; ++r) {
            float r2 = (float)(r * r);
            float dmax = fmaxf(fmaxf(d2[0], d2[1]), fmaxf(d2[2], d2[3]));
            if (__all(r2 >= dmax)) break;            // no radius >= r can improve
            int lo = j - r, hi = j + r;
            if (lo >= 0) {
                #pragma unroll
                for (int k = 0; k < 4; ++k)
                    d2[k] = fminf(d2[k], G[img][k][lo] + r2);
            }
            if (hi < WW) {
                #pragma unroll
                for (int k = 0; k < 4; ++k)
                    d2[k] = fminf(d2[k], G[img][k][hi] + r2);
            }
        }
        #pragma unroll
        for (int k = 0; k < 4; ++k)
            D[img][k][j] = sqrtf(d2[k]);
    }
    __syncthreads();

    // ---- phase 4: elementwise loss terms, 2 pixels per thread (preloaded)
    float sPT = 0.0f, sP = 0.0f, sT = 0.0f, sBCE = 0.0f, sFOC = 0.0f, sBND = 0.0f;
    #pragma unroll
    for (int e = 0; e < 2; ++e) {
        float x = e ? xv.y : xv.x;
        float t = e ? tv.y : tv.x;

        sBND += fabsf(D[0][k4][j4 + e] - D[1][k4][j4 + e]);

        float p   = 1.0f / (1.0f + expf(-x));
        float ax  = fabsf(x);
        float l1p = log1pf(expf(-ax));
        float bce_el = fmaxf(x, 0.0f) - x * t + l1p;   // BCEWithLogits
        float lsx  = fminf(x, 0.0f) - l1p;             // log(p)
        float lsnx = -fmaxf(x, 0.0f) - l1p;            // log(1-p)
        float bce_f = -(t * lsx + (1.0f - t) * lsnx);
        float pt = p * t + (1.0f - p) * (1.0f - t);
        float om = 1.0f - pt;

        sPT  += p * t;
        sP   += p;
        sT   += t;
        sBCE += bce_el;
        sFOC += om * om * bce_f;                       // alpha=1, gamma=2
    }

    // ---- block reduction (8 waves)
    float vals[6] = { sPT, sP, sT, sBCE, sFOC, sBND };
    int lane = tid & 63;
    int wave = tid >> 6;
    #pragma unroll
    for (int k = 0; k < 6; ++k) {
        float v = vals[k];
        #pragma unroll
        for (int off = 32; off > 0; off >>= 1)
            v += __shfl_down(v, off, 64);
        if (lane == 0) red[wave][k] = v;
    }
    __syncthreads();

    // tid==0 does ALL 6 partial stores itself so its own __threadfence orders
    // them before the ticket increment (fence only orders the issuing thread).
    if (tid == 0) {
        #pragma unroll
        for (int k = 0; k < 6; ++k) {
            float s = 0.0f;
            #pragma unroll
            for (int wv = 0; wv < 8; ++wv) s += red[wv][k];
            partial[blk * 8 + k] = s;
        }
        __threadfence();
        unsigned old = atomicAdd(&g_ticket, 1u);
        amLast = ((old & 255u) == 255u) ? 1 : 0;
    }
    __syncthreads();

    // ---- phase 5: last-arriving block combines all partials
    if (amLast) {
        float v[6] = { 0, 0, 0, 0, 0, 0 };
        if (tid < 256) {
            float* ps = partial + tid * 8;
            #pragma unroll
            for (int k = 0; k < 6; ++k)
                v[k] = atomicAdd(&ps[k], 0.0f);    // coherent read (bypasses L1)
        }
        #pragma unroll
        for (int k = 0; k < 6; ++k) {
            float x = v[k];
            #pragma unroll
            for (int off = 32; off > 0; off >>= 1)
                x += __shfl_down(x, off, 64);
            if (lane == 0) red[wave][k] = x;
        }
        __syncthreads();
        if (tid == 0) {
            float s[6];
            #pragma unroll
            for (int k = 0; k < 6; ++k)
                s[k] = red[0][k] + red[1][k] + red[2][k] + red[3][k]
                     + red[4][k] + red[5][k] + red[6][k] + red[7][k];
            float inter = s[0], sp = s[1], st = s[2];
            float bce = s[3], foc = s[4], bnd = s[5];
            float invN = 1.0f / (float)NN;
            float dice = 1.0f - (2.0f * inter + 1.0f) / (sp + st + 1.0f);
            out[0] = 0.5f * dice + 0.5f * (bce * invN)
                   + 0.1f * (bnd * invN) + 0.2f * (foc * invN);
        }
    }
}

extern "C" void kernel_launch(void* const* d_in, const int* in_sizes, int n_in,
                              void* d_out, int out_size, void* d_ws, size_t ws_size,
                              hipStream_t stream) {
    (void)in_sizes; (void)n_in; (void)out_size; (void)ws_size;
    const float* pred = (const float*)d_in[0];
    const float* targ = (const float*)d_in[1];
    float* ws = (float*)d_ws;

    fused_all<<<256, 512, 0, stream>>>(pred, targ, ws, (float*)d_out);
}

// Round 3
// 68.134 us; speedup vs baseline: 1.0734x; 1.0734x over previous
//
#include <hip/hip_runtime.h>
#include <math.h>

#define BB 4
#define HH 256
#define WW 256
#define NN (BB*HH*WW)          // 262144
typedef unsigned long long u64;
typedef unsigned int u32;

#define SENT 100000            // no-zero-in-column sentinel (g^2 ~1e10 >> 130050 max real)

// ws layout: float partial[block][8], blocks 0..255, only [0..5] used.
// Cacheline-padded (32B/block) plain stores -> no RMW atomics, no init needed.

// ---------------------------------------------------------------------------
// Kernel 1: fully fused. grid = 256 blocks (b, 4-row band), 512 threads.
//   phase 1+2: thread (img = tid>>8, c = tid&255) builds column c's zero
//              bitmask of image img in REGISTERS (reads are L2-resident),
//              bit-scans it for the band's 4 vertical distances -> LDS G.
//   phase 3:   thread (img, j) outward min-plus scan on its image only
//              (waves are img-uniform -> coherent __all early exit),
//              writes sqrt(d2) -> LDS D.
//   phase 4:   512 threads x 2 pixels elementwise loss terms,
//              block reduction, ONE plain 6-float store per block.
// ---------------------------------------------------------------------------
__global__ __launch_bounds__(512)
void fused_main(const float* __restrict__ pred,
                const float* __restrict__ targ,
                float* __restrict__ partial) {
    __shared__ float G[2][4][WW];   // vertical g^2  [img][band row][col]
    __shared__ float D[2][4][WW];   // sqrt(d2)      [img][band row][col]
    __shared__ float red[8][6];

    int blk  = blockIdx.x;          // 0..255
    int b    = blk >> 6;
    int band = blk & 63;
    int i0   = band << 2;           // first row of band
    int wq   = i0 >> 6;             // 64-row word containing the band
    int o0   = i0 & 63;             // bit offset (<=60, so o0+3 <= 63)

    int tid  = threadIdx.x;
    int img  = tid >> 8;            // waves 0-3: pred, waves 4-7: targ
    int c    = tid & 255;           // this thread's column

    // ---- phase 1: column zero-mask in registers (zero iff x <= 0.5)
    const float* s = (img ? targ : pred) + b * (HH * WW) + c;
    u64 M[4];
    #pragma unroll
    for (int w = 0; w < 4; ++w) {
        u64 m = 0;
        #pragma unroll
        for (int rr = 0; rr < 64; ++rr) {
            float x = s[(w * 64 + rr) * WW];
            m |= ((u64)(x <= 0.5f)) << rr;
        }
        M[w] = m;
    }

    // ---- phase 2: vertical distances for the band's 4 rows (verified bit logic)
    {
        u64 M0 = M[0], M1 = M[1], M2 = M[2], M3 = M[3];

        // per-word first (lowest) set-bit global index, sentinel SENT
        int t1 = __ffsll(M1), t2 = __ffsll(M2), t3 = __ffsll(M3);
        int f1 = t1 ? 64 + t1 - 1  : SENT;
        int f2 = t2 ? 128 + t2 - 1 : SENT;
        int f3 = t3 ? 192 + t3 - 1 : SENT;
        // per-word last (highest) set-bit global index, sentinel -SENT
        int r0 = __ffsll(__brevll(M0));
        int r1 = __ffsll(__brevll(M1));
        int r2 = __ffsll(__brevll(M2));
        int l0 = r0 ? 64 - r0  : -SENT;
        int l1 = r1 ? 128 - r1 : -SENT;
        int l2 = r2 ? 192 - r2 : -SENT;

        int s3 = f3;
        int s2 = min(f2, s3);
        int s1 = min(f1, s2);
        int NF = (wq == 0) ? s1 : (wq == 1) ? s2 : (wq == 2) ? s3 : SENT;
        int q0 = l0;
        int q1 = max(q0, l1);
        int q2 = max(q1, l2);
        int PB = (wq == 0) ? -SENT : (wq == 1) ? q0 : (wq == 2) ? q1 : q2;
        u64 Mq = (wq == 0) ? M0 : (wq == 1) ? M1 : (wq == 2) ? M2 : M3;

        #pragma unroll
        for (int kk = 0; kk < 4; ++kk) {
            int i = i0 + kk, o = o0 + kk;            // o <= 63
            u64 sh  = Mq >> o;                       // bits at/above i within word
            int tn  = __ffsll(sh);
            int n   = tn ? i + tn - 1 : NF;          // nearest zero row >= i
            u64 shl = Mq << (63 - o);                // bits at/below i within word
            int tp  = __ffsll(__brevll(shl));
            int p   = tp ? i - (tp - 1) : PB;        // nearest zero row <= i
            int g   = min(n - i, i - p);
            G[img][kk][c] = (float)g * (float)g;
        }
    }
    __syncthreads();

    // ---- phase 3: horizontal min-plus, outward scan, one image per thread
    {
        int j = c;
        float d2[4];
        #pragma unroll
        for (int k = 0; k < 4; ++k)
            d2[k] = G[img][k][j];                    // r = 0 candidate
        for (int r = 1; r < WW; ++r) {
            float r2 = (float)(r * r);
            float dmax = fmaxf(fmaxf(d2[0], d2[1]), fmaxf(d2[2], d2[3]));
            if (__all(r2 >= dmax)) break;            // no radius >= r can improve
            int lo = j - r, hi = j + r;
            if (lo >= 0) {
                #pragma unroll
                for (int k = 0; k < 4; ++k)
                    d2[k] = fminf(d2[k], G[img][k][lo] + r2);
            }
            if (hi < WW) {
                #pragma unroll
                for (int k = 0; k < 4; ++k)
                    d2[k] = fminf(d2[k], G[img][k][hi] + r2);
            }
        }
        #pragma unroll
        for (int k = 0; k < 4; ++k)
            D[img][k][j] = sqrtf(d2[k]);
    }
    __syncthreads();

    // ---- phase 4: elementwise loss terms, 2 pixels per thread
    float sPT = 0.0f, sP = 0.0f, sT = 0.0f, sBCE = 0.0f, sFOC = 0.0f, sBND = 0.0f;
    #pragma unroll
    for (int h = 0; h < 2; ++h) {
        int q  = tid + h * 512;                      // 0..1023 pixel in band
        int k  = q >> 8;                             // band row 0..3
        int j2 = q & 255;                            // col
        int idx = (b * HH + (i0 + k)) * WW + j2;
        float x = pred[idx];
        float t = targ[idx];

        sBND += fabsf(D[0][k][j2] - D[1][k][j2]);

        float p   = 1.0f / (1.0f + expf(-x));
        float ax  = fabsf(x);
        float l1p = log1pf(expf(-ax));
        float bce_el = fmaxf(x, 0.0f) - x * t + l1p;   // BCEWithLogits
        float lsx  = fminf(x, 0.0f) - l1p;             // log(p)
        float lsnx = -fmaxf(x, 0.0f) - l1p;            // log(1-p)
        float bce_f = -(t * lsx + (1.0f - t) * lsnx);
        float pt = p * t + (1.0f - p) * (1.0f - t);
        float om = 1.0f - pt;

        sPT  += p * t;
        sP   += p;
        sT   += t;
        sBCE += bce_el;
        sFOC += om * om * bce_f;                       // alpha=1, gamma=2
    }

    // ---- block reduction (8 waves), one plain padded store per block
    float vals[6] = { sPT, sP, sT, sBCE, sFOC, sBND };
    int lane = tid & 63;
    int wave = tid >> 6;
    #pragma unroll
    for (int k = 0; k < 6; ++k) {
        float v = vals[k];
        #pragma unroll
        for (int off = 32; off > 0; off >>= 1)
            v += __shfl_down(v, off, 64);
        if (lane == 0) red[wave][k] = v;
    }
    __syncthreads();
    if (tid < 6) {
        float s2 = 0.0f;
        #pragma unroll
        for (int wv = 0; wv < 8; ++wv) s2 += red[wv][tid];
        partial[blk * 8 + tid] = s2;                   // plain store, padded line
    }
}

// ---------------------------------------------------------------------------
// Kernel 2: reduce 256 x 6 partials, emit the scalar loss.
// Stream order guarantees visibility of kernel 1's stores.
// ---------------------------------------------------------------------------
__global__ __launch_bounds__(256)
void finalize(const float* __restrict__ partial, float* __restrict__ out) {
    __shared__ float red[4][6];
    int tid = threadIdx.x;
    float v[6];
    #pragma unroll
    for (int k = 0; k < 6; ++k) v[k] = partial[tid * 8 + k];

    int lane = tid & 63;
    int wave = tid >> 6;
    #pragma unroll
    for (int k = 0; k < 6; ++k) {
        float x = v[k];
        #pragma unroll
        for (int off = 32; off > 0; off >>= 1)
            x += __shfl_down(x, off, 64);
        if (lane == 0) red[wave][k] = x;
    }
    __syncthreads();
    if (tid == 0) {
        float inter = red[0][0] + red[1][0] + red[2][0] + red[3][0];
        float sp    = red[0][1] + red[1][1] + red[2][1] + red[3][1];
        float st    = red[0][2] + red[1][2] + red[2][2] + red[3][2];
        float bce   = red[0][3] + red[1][3] + red[2][3] + red[3][3];
        float foc   = red[0][4] + red[1][4] + red[2][4] + red[3][4];
        float bnd   = red[0][5] + red[1][5] + red[2][5] + red[3][5];
        float invN = 1.0f / (float)NN;
        float dice = 1.0f - (2.0f * inter + 1.0f) / (sp + st + 1.0f);
        out[0] = 0.5f * dice + 0.5f * (bce * invN)
               + 0.1f * (bnd * invN) + 0.2f * (foc * invN);
    }
}

extern "C" void kernel_launch(void* const* d_in, const int* in_sizes, int n_in,
                              void* d_out, int out_size, void* d_ws, size_t ws_size,
                              hipStream_t stream) {
    (void)in_sizes; (void)n_in; (void)out_size; (void)ws_size;
    const float* pred = (const float*)d_in[0];
    const float* targ = (const float*)d_in[1];
    float* ws = (float*)d_ws;

    fused_main<<<256, 512, 0, stream>>>(pred, targ, ws);
    finalize<<<1, 256, 0, stream>>>(ws, (float*)d_out);
}